// Round 15
// baseline (74.004 us; speedup 1.0000x reference)
//
#include <hip/hip_runtime.h>
#include <hip/hip_bf16.h>
#include <stdint.h>

#define SEQ  512
#define NB   256
#define SW   2048
#define STW  1792
#define INW  256
#define LINC 0.99999f

typedef float f32x4 __attribute__((ext_vector_type(4)));

// ---------------- workspace layout (bytes) ----------------
// [0,1KB):    flags[256]   (zeroed per replay via memset)
// [2048]:     abort flag
// [16KB, +1.92MB): xf8 — x(497+u) fp8 fragments, 15 slots x 128KB
// [2MB, 6MB):  W1f8 — 64 col-slices x 64KB, fragment order
// [6MB,10MB):  W2f8 — 64 col-slices x 64KB, fragment order
// [10MB,14MB): H8 — 8 slots x 512KB (t = 504+tt), chunk-major
#define WS_ABORT 2048
#define WS_XF8   16384
#define XF8SLOT  131072
#define WS_W1F8  (2*1024*1024)
#define WS_W2F8  (6*1024*1024)
#define WS_H8    (10*1024*1024)
#define H8SLOT   524288

// chunk-major fp8 (proven R2-R14): element(lane l, byte b) of chunk c, strip st:
//   row = st*16 + (l&15), k = c*32 + (l>>4)*8 + b ; u64 at (st*NC + c)*512 + l*8

// ---------- proven comm primitives (R5-R7): sc1 stores, sc1 flag polls,
// plain cacheable data loads after flag observation ----------
__device__ __forceinline__ unsigned ald32(const void* p){
  return __hip_atomic_load((const unsigned*)p, __ATOMIC_RELAXED, __HIP_MEMORY_SCOPE_AGENT);
}
__device__ __forceinline__ void ast64(void* p, uint64_t v){
  __hip_atomic_store((uint64_t*)p, v, __ATOMIC_RELAXED, __HIP_MEMORY_SCOPE_AGENT);
}
__device__ __forceinline__ void ast32(void* p, unsigned v){
  __hip_atomic_store((unsigned*)p, v, __ATOMIC_RELAXED, __HIP_MEMORY_SCOPE_AGENT);
}

__device__ __forceinline__ uint64_t pack8(const float* f){
  int lo = 0, hi = 0;
  lo = __builtin_amdgcn_cvt_pk_fp8_f32(f[0], f[1], lo, false);
  lo = __builtin_amdgcn_cvt_pk_fp8_f32(f[2], f[3], lo, true);
  hi = __builtin_amdgcn_cvt_pk_fp8_f32(f[4], f[5], hi, false);
  hi = __builtin_amdgcn_cvt_pk_fp8_f32(f[6], f[7], hi, true);
  return (uint64_t)(uint32_t)lo | ((uint64_t)(uint32_t)hi << 32);
}
__device__ __forceinline__ uint64_t pack8v(float4 a, float4 b){
  int lo = 0, hi = 0;
  lo = __builtin_amdgcn_cvt_pk_fp8_f32(a.x, a.y, lo, false);
  lo = __builtin_amdgcn_cvt_pk_fp8_f32(a.z, a.w, lo, true);
  hi = __builtin_amdgcn_cvt_pk_fp8_f32(b.x, b.y, hi, false);
  hi = __builtin_amdgcn_cvt_pk_fp8_f32(b.z, b.w, hi, true);
  return (uint64_t)(uint32_t)lo | ((uint64_t)(uint32_t)hi << 32);
}
__device__ __forceinline__ f32x4 mf(uint64_t a, long b, f32x4 c){
  return __builtin_amdgcn_mfma_f32_16x16x32_fp8_fp8((long)a, b, c, 0, 0, 0);
}

// per-lane dataflow wait: lane polls flags[prod] (prod = -1 -> satisfied)
__device__ __forceinline__ void waitflags(unsigned* flags, unsigned tgt, int prod,
                                          unsigned* abortf, int* s_dead)
{
  if (*s_dead) return;
  long long start = clock64(); int it = 0;
  for (;;){
    unsigned f = (prod >= 0) ? ald32(flags + prod) : tgt;
    if (__ballot(f >= tgt) == ~0ull) break;
    if (((++it) & 15) == 0){
      if (ald32(abortf) != 0u){ *s_dead = 1; break; }
      if (clock64() - start > 40000000LL){ ast32(abortf, 1u); *s_dead = 1; break; }
    }
    __builtin_amdgcn_s_sleep(1);
  }
}

// ============ kernel A: prep share -> flag -> hk2 GEMM (fused) ============
// grid 256 (= CU count, all co-resident) x 512 thr.
// prep share: blk<128 -> W1 half-slice (sc1); blk>=128 -> W2 half-slice (plain,
// consumed next kernel); blk<60 also converts x-unit blk on tid>=256 (sc1).
// hk2: block (tt,cq) = H(504+tt) cols cq*64..+64; waits 36 producer flags.
__global__ __launch_bounds__(512, 2)
void fusedA(const float* __restrict__ x, const float* __restrict__ W1,
            const float* __restrict__ W2, const float* __restrict__ b1,
            uint8_t* __restrict__ ws)
{
  __shared__ uint8_t Wl[131072];
  __shared__ uint8_t xfer8[16384];
  __shared__ int s_dead;
  const int blk = blockIdx.x;
  const int tt  = blk >> 5, cq = blk & 31;
  const int tid = threadIdx.x, lane = tid & 63, wv = tid >> 6, l15 = lane & 15;
  const int s0  = wv*2;

  unsigned* flags  = (unsigned*)ws;
  unsigned* abortf = (unsigned*)(ws + WS_ABORT);
  if (tid == 0) s_dead = 0;

  // ---- prep share ----
  if (tid < 256){
    const bool isw2 = blk >= 128;
    const int unit  = blk & 127;
    const int sc = unit >> 1, hf = unit & 1;
    uint8_t* dstb = ws + (isw2 ? WS_W2F8 : WS_W1F8) + (size_t)sc*65536;
    const int jc  = (tid >> 4) + hf*16;
    const int kc0 = (tid & 15) * 8;
    const float* r = (isw2 ? W2 : W1) + (size_t)(sc*32 + jc)*SW;
    #pragma unroll
    for (int p = 0; p < 16; ++p){
      const int k = kc0 + p*128;
      const int dst = (k >> 5)*1024 + (jc >> 4)*512
                    + (((jc & 15) + (((k >> 3) & 3) << 4)) << 3);
      uint64_t v = pack8v(*(const float4*)(r + k), *(const float4*)(r + k + 4));
      if (isw2) *(uint64_t*)(dstb + dst) = v;      // consumed after kernel boundary
      else      ast64(dstb + dst, v);              // consumed in-kernel
    }
  } else if (blk < 60){
    const int tid2 = tid - 256;
    const int u = blk >> 2, q = blk & 3;           // x-unit = blk
    uint8_t* dst = ws + WS_XF8 + (size_t)u*XF8SLOT;
    #pragma unroll
    for (int rr = 0; rr < 8; ++rr){
      const int linear = rr*256 + tid2;
      const int stl = linear >> 9;
      const int rem = linear & 511;
      const int c = rem >> 6, l = rem & 63;
      const int st = q*4 + stl;
      const int row = st*16 + (l & 15);
      const int col = c*32 + ((l >> 4) << 3);
      const float* xp = x + ((size_t)(497 + u)*NB + row)*INW + col;
      float vv[8];
      *(float4*)&vv[0] = *(const float4*)xp;
      *(float4*)&vv[4] = *(const float4*)(xp + 4);
      ast64(dst + (size_t)(st*8 + c)*512 + l*8, pack8(vv));
    }
  }
  __syncthreads();                                 // drain sc1 stores (vmcnt 0)
  if (tid == 0) ast32(&flags[blk], 1u);

  // ---- wait producers: lanes 0..31 -> x blocks 4tt+lane; 32..35 -> W1 blocks 4cq+..
  int prod = -1;
  if (lane < 32)      prod = 4*tt + lane;
  else if (lane < 36) prod = 4*cq + (lane - 32);
  waitflags(flags, 1u, prod, abortf, &s_dead);
  asm volatile("" ::: "memory");

  // ---- hk2 body (verbatim R14) ----
  { // stage both W1 slices
    const uint64_t* src = (const uint64_t*)(ws + WS_W1F8 + (size_t)(cq*2)*65536);
    uint64_t* dst = (uint64_t*)Wl;
    #pragma unroll
    for (int k = 0; k < 32; ++k) dst[tid + k*512] = src[tid + k*512];
  }
  float b1v[4];
  #pragma unroll
  for (int f = 0; f < 4; ++f) b1v[f] = b1[cq*64 + f*16 + l15];
  __syncthreads();

  const uint8_t* xf = ws + WS_XF8 + lane*8;
  f32x4 acc[2][4] = {};
  for (int c0 = 0; c0 < 64; c0 += 8){
    const int j = c0 >> 3;
    const uint8_t* slot = xf + (size_t)(7 + tt - j)*XF8SLOT;
    uint64_t a0[8], a1[8];
    #pragma unroll
    for (int i = 0; i < 8; ++i){
      a0[i] = *(const uint64_t*)(slot + (size_t)( s0     *8 + i)*512);
      a1[i] = *(const uint64_t*)(slot + (size_t)((s0 + 1)*8 + i)*512);
    }
    #pragma unroll
    for (int i = 0; i < 8; ++i){
      const uint8_t* bp = Wl + (size_t)(c0 + i)*1024 + lane*8;
      #pragma unroll
      for (int f = 0; f < 4; ++f){
        long b = *(const long*)(bp + (f >> 1)*65536 + (f & 1)*512);
        acc[0][f] = mf(a0[i], b, acc[0][f]);
        acc[1][f] = mf(a1[i], b, acc[1][f]);
      }
    }
  }

  #pragma unroll
  for (int s = 0; s < 2; ++s)
    #pragma unroll
    for (int f = 0; f < 4; ++f)
      #pragma unroll
      for (int i = 0; i < 4; ++i){
        const int row = (s0 + s)*16 + ((lane >> 4) << 2) + i;
        float h = fmaxf(acc[s][f][i] + b1v[f], 0.f);
        int pk = __builtin_amdgcn_cvt_pk_fp8_f32(h, 0.f, 0, false);
        xfer8[row*64 + f*16 + l15] = (uint8_t)(pk & 0xFF);
      }
  __syncthreads();
  uint8_t* h8 = ws + WS_H8 + (size_t)tt*H8SLOT;
  #pragma unroll
  for (int r = 0; r < 4; ++r){
    const int slot = tid + r*512;
    const int st = slot >> 7, cc = (slot >> 6) & 1, l = slot & 63;
    uint64_t v = *(const uint64_t*)
      &xfer8[(st*16 + (l & 15))*64 + cc*32 + ((l >> 4) << 3)];
    *(uint64_t*)(h8 + (size_t)(st*64 + cq*2 + cc)*512 + l*8) = v;
  }
}

// ============ kernel B: corr GEMM + direct f32 atomic assembly into out ======
// grid 576 = 288 (j,cb) units x 2 row-halves; 256 thr. W2 slice (64KB) in LDS.
// out[c] += UM*LIN^j*(H(511-j)@W2^T + b2)[c-256j]  (+ LIN^(j+1)*x term if cb<8)
__global__ __launch_bounds__(256, 2)
void corrB(const float* __restrict__ x, const float* __restrict__ b2,
           float* __restrict__ out, uint8_t* __restrict__ ws)
{
  __shared__ uint8_t Wl[65536];
  const int blk = blockIdx.x;
  const int unit = blk >> 1, h = blk & 1;
  int j = 0, base = 0;
  while (unit - base >= 64 - 8*j){ base += 64 - 8*j; ++j; }
  const int cb = unit - base;
  const int tt = 7 - j;
  const int tid = threadIdx.x, lane = tid & 63, wv = tid >> 6, l15 = lane & 15;
  const int s0 = h*8 + wv*2;

  { // stage W2 slice cb
    const uint64_t* src = (const uint64_t*)(ws + WS_W2F8 + (size_t)cb*65536);
    uint64_t* dst = (uint64_t*)Wl;
    #pragma unroll
    for (int k = 0; k < 32; ++k) dst[tid + k*256] = src[tid + k*256];
  }
  const float b2v0 = b2[cb*32 + l15];
  const float b2v1 = b2[cb*32 + 16 + l15];
  __syncthreads();

  const uint8_t* h8 = ws + WS_H8 + (size_t)tt*H8SLOT + lane*8;
  const uint8_t* A0 = h8 + (size_t)( s0     *64)*512;
  const uint8_t* A1 = h8 + (size_t)((s0 + 1)*64)*512;

  f32x4 acc[2][2] = {{{0,0,0,0},{0,0,0,0}},{{0,0,0,0},{0,0,0,0}}};
  for (int c0 = 0; c0 < 64; c0 += 8){
    uint64_t a0[8], a1[8];
    #pragma unroll
    for (int i = 0; i < 8; ++i){
      a0[i] = *(const uint64_t*)(A0 + (size_t)(c0 + i)*512);
      a1[i] = *(const uint64_t*)(A1 + (size_t)(c0 + i)*512);
    }
    #pragma unroll
    for (int i = 0; i < 8; ++i){
      const uint8_t* bp = Wl + (size_t)(c0 + i)*1024 + lane*8;
      long b0 = *(const long*)bp, b1q = *(const long*)(bp + 512);
      acc[0][0] = mf(a0[i], b0,  acc[0][0]);
      acc[0][1] = mf(a0[i], b1q, acc[0][1]);
      acc[1][0] = mf(a1[i], b0,  acc[1][0]);
      acc[1][1] = mf(a1[i], b1q, acc[1][1]);
    }
  }

  const float UM = (float)(1.0 - 0.99999);
  float linp[9]; linp[0] = 1.f;
  #pragma unroll
  for (int p = 1; p < 9; ++p) linp[p] = linp[p-1]*LINC;
  const float cj = UM * linp[j];

  #pragma unroll
  for (int s = 0; s < 2; ++s)
    #pragma unroll
    for (int f = 0; f < 2; ++f)
      #pragma unroll
      for (int i = 0; i < 4; ++i){
        const int row = (s0 + s)*16 + ((lane >> 4) << 2) + i;
        const int cl  = cb*32 + f*16 + l15;     // local col (within corr)
        const int c   = cl + 256*j;             // global out col
        float contrib = cj * (acc[s][f][i] + (f ? b2v1 : b2v0));
        if (cb < 8)                              // this unit owns the x-term (J == j)
          contrib += linp[j+1] * x[((size_t)(511 - j)*NB + row)*INW + cl];
        float* addr = (c < STW) ? out + NB*INW + (size_t)row*STW + c
                                : out + (size_t)row*INW + (c - STW);
        atomicAdd(addr, contrib);
      }
}

extern "C" void kernel_launch(void* const* d_in, const int* in_sizes, int n_in,
                              void* d_out, int out_size, void* d_ws, size_t ws_size,
                              hipStream_t stream)
{
  const float* x   = (const float*)d_in[0];
  // d_in[1] (initial_state) provably does not reach the returned final carry
  const float* W1  = (const float*)d_in[2];
  const float* b1  = (const float*)d_in[3];
  const float* W2  = (const float*)d_in[4];
  const float* b2  = (const float*)d_in[5];
  float* out  = (float*)d_out;
  uint8_t* ws = (uint8_t*)d_ws;

  hipMemsetAsync(ws, 0, 4096, stream);                       // flags + abort
  hipMemsetAsync(d_out, 0, (size_t)out_size*4, stream);      // atomic accum target
  hipLaunchKernelGGL(fusedA, dim3(256), dim3(512), 0, stream, x, W1, W2, b1, ws);
  hipLaunchKernelGGL(corrB,  dim3(576), dim3(256), 0, stream, x, b2, out, ws);
}

// Round 17
// 68.162 us; speedup vs baseline: 1.0857x; 1.0857x over previous
//
#include <hip/hip_runtime.h>
#include <hip/hip_bf16.h>
#include <stdint.h>

#define SEQ  512
#define NB   256
#define SW   2048
#define STW  1792
#define INW  256
#define LINC 0.99999f

typedef float f32x4 __attribute__((ext_vector_type(4)));

// ---------------- workspace layout (bytes) ----------------
// [0,512):   flags[128] for corrAsk j=0 units   (zeroed per replay, 1KB memset)
// [512]:     abort flag
// [16KB, +1.92MB): xf8 — x(497+u) fp8 fragments, 15 slots x 128KB
// [2MB, 6MB):  W1f8 — 64 col-slices x 64KB, fragment order
// [6MB,10MB):  W2f8 — 64 col-slices x 64KB, fragment order
// [10MB,14MB): H8 — 8 slots x 512KB (t = 504+tt), chunk-major
#define WS_ABORT 512
#define WS_XF8   16384
#define XF8SLOT  131072
#define WS_W1F8  (2*1024*1024)
#define WS_W2F8  (6*1024*1024)
#define WS_H8    (10*1024*1024)
#define H8SLOT   524288

// chunk-major fp8 (proven R2-R15): element(lane l, byte b) of chunk c, strip st:
//   row = st*16 + (l&15), k = c*32 + (l>>4)*8 + b ; u64 at (st*NC + c)*512 + l*8

// ---------- proven comm primitives: sc1 stores, sc1 flag polls ----------
__device__ __forceinline__ unsigned ald32(const void* p){
  return __hip_atomic_load((const unsigned*)p, __ATOMIC_RELAXED, __HIP_MEMORY_SCOPE_AGENT);
}
__device__ __forceinline__ void ast32(void* p, unsigned v){
  __hip_atomic_store((unsigned*)p, v, __ATOMIC_RELAXED, __HIP_MEMORY_SCOPE_AGENT);
}

__device__ __forceinline__ uint64_t pack8(const float* f){
  int lo = 0, hi = 0;
  lo = __builtin_amdgcn_cvt_pk_fp8_f32(f[0], f[1], lo, false);
  lo = __builtin_amdgcn_cvt_pk_fp8_f32(f[2], f[3], lo, true);
  hi = __builtin_amdgcn_cvt_pk_fp8_f32(f[4], f[5], hi, false);
  hi = __builtin_amdgcn_cvt_pk_fp8_f32(f[6], f[7], hi, true);
  return (uint64_t)(uint32_t)lo | ((uint64_t)(uint32_t)hi << 32);
}
__device__ __forceinline__ uint64_t pack8v(float4 a, float4 b){
  int lo = 0, hi = 0;
  lo = __builtin_amdgcn_cvt_pk_fp8_f32(a.x, a.y, lo, false);
  lo = __builtin_amdgcn_cvt_pk_fp8_f32(a.z, a.w, lo, true);
  hi = __builtin_amdgcn_cvt_pk_fp8_f32(b.x, b.y, hi, false);
  hi = __builtin_amdgcn_cvt_pk_fp8_f32(b.z, b.w, hi, true);
  return (uint64_t)(uint32_t)lo | ((uint64_t)(uint32_t)hi << 32);
}
__device__ __forceinline__ f32x4 mf(uint64_t a, long b, f32x4 c){
  return __builtin_amdgcn_mfma_f32_16x16x32_fp8_fp8((long)a, b, c, 0, 0, 0);
}

// ============ prep: all fp32->fp8 conversion, once (verbatim R14) ============
__global__ __launch_bounds__(256)
void prep(const float* __restrict__ x, const float* __restrict__ W1,
          const float* __restrict__ W2, uint8_t* __restrict__ ws)
{
  const int blk = blockIdx.x, tid = threadIdx.x;
  if (blk < 256){
    const bool isw2 = blk >= 128;
    const int unit  = blk & 127;
    const int sc = unit >> 1, hf = unit & 1;
    uint8_t* dstb = ws + (isw2 ? WS_W2F8 : WS_W1F8) + (size_t)sc*65536;
    const int jc  = (tid >> 4) + hf*16;
    const int kc0 = (tid & 15) * 8;
    const float* r = (isw2 ? W2 : W1) + (size_t)(sc*32 + jc)*SW;
    #pragma unroll
    for (int p = 0; p < 16; ++p){
      const int k = kc0 + p*128;
      const int dst = (k >> 5)*1024 + (jc >> 4)*512
                    + (((jc & 15) + (((k >> 3) & 3) << 4)) << 3);
      *(uint64_t*)(dstb + dst) =
        pack8v(*(const float4*)(r + k), *(const float4*)(r + k + 4));
    }
  } else {
    const int unit = blk - 256;                   // 0..59
    const int u = unit >> 2, q = unit & 3;        // slot 0..14, strip-quarter
    uint8_t* dst = ws + WS_XF8 + (size_t)u*XF8SLOT;
    #pragma unroll
    for (int rr = 0; rr < 8; ++rr){
      const int linear = rr*256 + tid;
      const int stl = linear >> 9;
      const int rem = linear & 511;
      const int c = rem >> 6, l = rem & 63;
      const int st = q*4 + stl;
      const int row = st*16 + (l & 15);
      const int col = c*32 + ((l >> 4) << 3);
      const float* xp = x + ((size_t)(497 + u)*NB + row)*INW + col;
      float vv[8];
      *(float4*)&vv[0] = *(const float4*)xp;
      *(float4*)&vv[4] = *(const float4*)(xp + 4);
      *(uint64_t*)(dst + (size_t)(st*8 + c)*512 + l*8) = pack8(vv);
    }
  }
}

// ============ hk2: H(504+tt) = relu(s~ @ W1^T + b1) (verbatim R14) ============
__global__ __launch_bounds__(512, 2)
void hk2(const float* __restrict__ b1, uint8_t* __restrict__ ws)
{
  __shared__ uint8_t Wl[131072];
  __shared__ uint8_t xfer8[16384];
  const int blk = blockIdx.x;
  const int tt  = blk >> 5, cq = blk & 31;
  const int tid = threadIdx.x, lane = tid & 63, wv = tid >> 6, l15 = lane & 15;
  const int s0  = wv*2;

  {
    const uint64_t* src = (const uint64_t*)(ws + WS_W1F8 + (size_t)(cq*2)*65536);
    uint64_t* dst = (uint64_t*)Wl;
    #pragma unroll
    for (int k = 0; k < 32; ++k) dst[tid + k*512] = src[tid + k*512];
  }
  float b1v[4];
  #pragma unroll
  for (int f = 0; f < 4; ++f) b1v[f] = b1[cq*64 + f*16 + l15];
  __syncthreads();

  const uint8_t* xf = ws + WS_XF8 + lane*8;
  f32x4 acc[2][4] = {};
  for (int c0 = 0; c0 < 64; c0 += 8){
    const int j = c0 >> 3;
    const uint8_t* slot = xf + (size_t)(7 + tt - j)*XF8SLOT;
    uint64_t a0[8], a1[8];
    #pragma unroll
    for (int i = 0; i < 8; ++i){
      a0[i] = *(const uint64_t*)(slot + (size_t)( s0     *8 + i)*512);
      a1[i] = *(const uint64_t*)(slot + (size_t)((s0 + 1)*8 + i)*512);
    }
    #pragma unroll
    for (int i = 0; i < 8; ++i){
      const uint8_t* bp = Wl + (size_t)(c0 + i)*1024 + lane*8;
      #pragma unroll
      for (int f = 0; f < 4; ++f){
        long b = *(const long*)(bp + (f >> 1)*65536 + (f & 1)*512);
        acc[0][f] = mf(a0[i], b, acc[0][f]);
        acc[1][f] = mf(a1[i], b, acc[1][f]);
      }
    }
  }

  #pragma unroll
  for (int s = 0; s < 2; ++s)
    #pragma unroll
    for (int f = 0; f < 4; ++f)
      #pragma unroll
      for (int i = 0; i < 4; ++i){
        const int row = (s0 + s)*16 + ((lane >> 4) << 2) + i;
        float h = fmaxf(acc[s][f][i] + b1v[f], 0.f);
        int pk = __builtin_amdgcn_cvt_pk_fp8_f32(h, 0.f, 0, false);
        xfer8[row*64 + f*16 + l15] = (uint8_t)(pk & 0xFF);
      }
  __syncthreads();
  uint8_t* h8 = ws + WS_H8 + (size_t)tt*H8SLOT;
  #pragma unroll
  for (int r = 0; r < 4; ++r){
    const int slot = tid + r*512;
    const int st = slot >> 7, cc = (slot >> 6) & 1, l = slot & 63;
    uint64_t v = *(const uint64_t*)
      &xfer8[(st*16 + (l & 15))*64 + cc*32 + ((l >> 4) << 3)];
    *(uint64_t*)(h8 + (size_t)(st*64 + cq*2 + cc)*512 + l*8) = v;
  }
}

// ============ corrAsk: corr GEMM + in-kernel assembly ============
// 576 blocks x 256 thr. Blocks 0..127 = j=0 units (cb,h): WRITE base value
// (covers every out column) via sc1, publish flag. Blocks 128..575 = j>=1:
// GEMM first, wait single producer flag (cb+8j,h), then atomicAdd contribution.
__global__ __launch_bounds__(256, 2)
void corrAsk(const float* __restrict__ x, const float* __restrict__ b2,
             float* __restrict__ out, uint8_t* __restrict__ ws)
{
  __shared__ uint8_t Wl[65536];
  __shared__ int s_dead;
  const int blk = blockIdx.x;
  int j, cb, h;
  if (blk < 128){ j = 0; cb = blk >> 1; h = blk & 1; }
  else {
    int b2i = blk - 128, base = 0; j = 1;
    while (b2i - base >= 2*(64 - 8*j)){ base += 2*(64 - 8*j); ++j; }
    const int rem = b2i - base; cb = rem >> 1; h = rem & 1;
  }
  const int tt = 7 - j;
  const int tid = threadIdx.x, lane = tid & 63, wv = tid >> 6, l15 = lane & 15;
  const int s0 = h*8 + wv*2;

  unsigned* flags  = (unsigned*)ws;
  unsigned* abortf = (unsigned*)(ws + WS_ABORT);
  if (tid == 0) s_dead = 0;

  { // stage W2 slice cb (verbatim R14)
    const uint64_t* src = (const uint64_t*)(ws + WS_W2F8 + (size_t)cb*65536);
    uint64_t* dst = (uint64_t*)Wl;
    #pragma unroll
    for (int k = 0; k < 32; ++k) dst[tid + k*256] = src[tid + k*256];
  }
  const float b2v0 = b2[cb*32 + l15];
  const float b2v1 = b2[cb*32 + 16 + l15];
  __syncthreads();

  const uint8_t* h8 = ws + WS_H8 + (size_t)tt*H8SLOT + lane*8;
  const uint8_t* A0 = h8 + (size_t)( s0     *64)*512;
  const uint8_t* A1 = h8 + (size_t)((s0 + 1)*64)*512;

  f32x4 acc[2][2] = {{{0,0,0,0},{0,0,0,0}},{{0,0,0,0},{0,0,0,0}}};
  for (int c0 = 0; c0 < 64; c0 += 8){
    uint64_t a0[8], a1[8];
    #pragma unroll
    for (int i = 0; i < 8; ++i){
      a0[i] = *(const uint64_t*)(A0 + (size_t)(c0 + i)*512);
      a1[i] = *(const uint64_t*)(A1 + (size_t)(c0 + i)*512);
    }
    #pragma unroll
    for (int i = 0; i < 8; ++i){
      const uint8_t* bp = Wl + (size_t)(c0 + i)*1024 + lane*8;
      long b0 = *(const long*)bp, b1q = *(const long*)(bp + 512);
      acc[0][0] = mf(a0[i], b0,  acc[0][0]);
      acc[0][1] = mf(a0[i], b1q, acc[0][1]);
      acc[1][0] = mf(a1[i], b0,  acc[1][0]);
      acc[1][1] = mf(a1[i], b1q, acc[1][1]);
    }
  }

  const float UM = (float)(1.0 - 0.99999);
  float linp[9]; linp[0] = 1.f;
  #pragma unroll
  for (int p = 1; p < 9; ++p) linp[p] = linp[p-1]*LINC;
  const float cj = UM * linp[j];

  if (j == 0){
    const int J = cb >> 3;                  // J = c>>8, constant per cb
    const float xw = linp[J + 1];
    #pragma unroll
    for (int s = 0; s < 2; ++s)
      #pragma unroll
      for (int f = 0; f < 2; ++f)
        #pragma unroll
        for (int i = 0; i < 4; ++i){
          const int row = (s0 + s)*16 + ((lane >> 4) << 2) + i;
          const int c   = cb*32 + f*16 + l15;
          float v = cj * (acc[s][f][i] + (f ? b2v1 : b2v0))
                  + xw * x[((size_t)(511 - J)*NB + row)*INW + (c & 255)];
          float* addr = (c < STW) ? out + NB*INW + (size_t)row*STW + c
                                  : out + (size_t)row*INW + (c - STW);
          ast32(addr, __float_as_uint(v));  // sc1: device-visible base write
        }
    __syncthreads();                        // drain sc1 stores (vmcnt 0)
    if (tid == 0) ast32(&flags[(cb << 1) | h], 1u);
  } else {
    // wait on the single j=0 producer covering our out columns
    if (!s_dead){
      const unsigned* fp = flags + (((cb + 8*j) << 1) | h);
      long long start = clock64(); int it = 0;
      for (;;){
        if (__ballot(ald32(fp) >= 1u) == ~0ull) break;
        if (((++it) & 15) == 0){
          if (ald32(abortf) != 0u){ if (tid == 0) s_dead = 1; break; }
          if (clock64() - start > 40000000LL){ ast32(abortf, 1u); break; }
        }
        __builtin_amdgcn_s_sleep(1);
      }
    }
    asm volatile("" ::: "memory");
    #pragma unroll
    for (int s = 0; s < 2; ++s)
      #pragma unroll
      for (int f = 0; f < 2; ++f)
        #pragma unroll
        for (int i = 0; i < 4; ++i){
          const int row = (s0 + s)*16 + ((lane >> 4) << 2) + i;
          const int c   = cb*32 + f*16 + l15 + 256*j;
          float contrib = cj * (acc[s][f][i] + (f ? b2v1 : b2v0));
          float* addr = (c < STW) ? out + NB*INW + (size_t)row*STW + c
                                  : out + (size_t)row*INW + (c - STW);
          atomicAdd(addr, contrib);
        }
  }
}

extern "C" void kernel_launch(void* const* d_in, const int* in_sizes, int n_in,
                              void* d_out, int out_size, void* d_ws, size_t ws_size,
                              hipStream_t stream)
{
  const float* x   = (const float*)d_in[0];
  // d_in[1] (initial_state) provably does not reach the returned final carry
  const float* W1  = (const float*)d_in[2];
  const float* b1  = (const float*)d_in[3];
  const float* W2  = (const float*)d_in[4];
  const float* b2  = (const float*)d_in[5];
  float* out  = (float*)d_out;
  uint8_t* ws = (uint8_t*)d_ws;

  (void)hipMemsetAsync(ws, 0, 1024, stream);   // flags + abort only (tiny)
  hipLaunchKernelGGL(prep,    dim3(316), dim3(256), 0, stream, x, W1, W2, ws);
  hipLaunchKernelGGL(hk2,     dim3(256), dim3(512), 0, stream, b1, ws);
  hipLaunchKernelGGL(corrAsk, dim3(576), dim3(256), 0, stream, x, b2, out, ws);
}

// Round 18
// 67.407 us; speedup vs baseline: 1.0979x; 1.0112x over previous
//
#include <hip/hip_runtime.h>
#include <hip/hip_bf16.h>
#include <stdint.h>

#define SEQ  512
#define NB   256
#define SW   2048
#define STW  1792
#define INW  256
#define LINC 0.99999f

typedef float f32x4 __attribute__((ext_vector_type(4)));

// ---------------- workspace layout (bytes) ----------------
// [0, 2MB):   xf8 — x(497+u) fp8 fragments, 15 slots x 128KB   (dead after hk2)
// [2MB, 6MB): W1f8 — 64 col-slices x 64KB, fragment order       (dead after hk2)
// [6MB,10MB): W2f8 — 64 col-slices x 64KB, fragment order
// [10MB,14MB): H8 — 8 slots x 512KB (t = 504+tt), chunk-major
// [0, 4.72MB): corr bf16 slabs (ALIASES xf8+W1f8 — both dead when corr2 runs)
#define WS_XF8   0
#define XF8SLOT  131072
#define WS_W1F8  (2*1024*1024)
#define WS_W2F8  (6*1024*1024)
#define WS_H8    (10*1024*1024)
#define H8SLOT   524288
#define WS_CORR  0

// chunk-major fp8 (proven R2-R17): element(lane l, byte b) of chunk c, strip st:
//   row = st*16 + (l&15), k = c*32 + (l>>4)*8 + b ; u64 at (st*NC + c)*512 + l*8

__device__ __forceinline__ uint64_t pack8(const float* f){
  int lo = 0, hi = 0;
  lo = __builtin_amdgcn_cvt_pk_fp8_f32(f[0], f[1], lo, false);
  lo = __builtin_amdgcn_cvt_pk_fp8_f32(f[2], f[3], lo, true);
  hi = __builtin_amdgcn_cvt_pk_fp8_f32(f[4], f[5], hi, false);
  hi = __builtin_amdgcn_cvt_pk_fp8_f32(f[6], f[7], hi, true);
  return (uint64_t)(uint32_t)lo | ((uint64_t)(uint32_t)hi << 32);
}
__device__ __forceinline__ uint64_t pack8v(float4 a, float4 b){
  int lo = 0, hi = 0;
  lo = __builtin_amdgcn_cvt_pk_fp8_f32(a.x, a.y, lo, false);
  lo = __builtin_amdgcn_cvt_pk_fp8_f32(a.z, a.w, lo, true);
  hi = __builtin_amdgcn_cvt_pk_fp8_f32(b.x, b.y, hi, false);
  hi = __builtin_amdgcn_cvt_pk_fp8_f32(b.z, b.w, hi, true);
  return (uint64_t)(uint32_t)lo | ((uint64_t)(uint32_t)hi << 32);
}
__device__ __forceinline__ f32x4 mf(uint64_t a, long b, f32x4 c){
  return __builtin_amdgcn_mfma_f32_16x16x32_fp8_fp8((long)a, b, c, 0, 0, 0);
}

// ============ prep: all fp32->fp8 conversion, once ============
__global__ __launch_bounds__(256)
void prep(const float* __restrict__ x, const float* __restrict__ W1,
          const float* __restrict__ W2, uint8_t* __restrict__ ws)
{
  const int blk = blockIdx.x, tid = threadIdx.x;
  if (blk < 256){
    const bool isw2 = blk >= 128;
    const int unit  = blk & 127;
    const int sc = unit >> 1, hf = unit & 1;
    uint8_t* dstb = ws + (isw2 ? WS_W2F8 : WS_W1F8) + (size_t)sc*65536;
    const int jc  = (tid >> 4) + hf*16;
    const int kc0 = (tid & 15) * 8;
    const float* r = (isw2 ? W2 : W1) + (size_t)(sc*32 + jc)*SW;
    #pragma unroll
    for (int p = 0; p < 16; ++p){
      const int k = kc0 + p*128;
      const int dst = (k >> 5)*1024 + (jc >> 4)*512
                    + (((jc & 15) + (((k >> 3) & 3) << 4)) << 3);
      *(uint64_t*)(dstb + dst) =
        pack8v(*(const float4*)(r + k), *(const float4*)(r + k + 4));
    }
  } else {
    const int unit = blk - 256;                   // 0..59
    const int u = unit >> 2, q = unit & 3;        // slot 0..14, strip-quarter
    uint8_t* dst = ws + WS_XF8 + (size_t)u*XF8SLOT;
    #pragma unroll
    for (int rr = 0; rr < 8; ++rr){
      const int linear = rr*256 + tid;
      const int stl = linear >> 9;
      const int rem = linear & 511;
      const int c = rem >> 6, l = rem & 63;
      const int st = q*4 + stl;
      const int row = st*16 + (l & 15);
      const int col = c*32 + ((l >> 4) << 3);
      const float* xp = x + ((size_t)(497 + u)*NB + row)*INW + col;
      float vv[8];
      *(float4*)&vv[0] = *(const float4*)xp;
      *(float4*)&vv[4] = *(const float4*)(xp + 4);
      *(uint64_t*)(dst + (size_t)(st*8 + c)*512 + l*8) = pack8(vv);
    }
  }
}

// ============ hk2: H(504+tt) = relu(s~ @ W1^T + b1) ============
// grid 256 (tt x 32 col-pairs) x 512 thr. W1 (2 slices, 128KB) staged in LDS;
// B-reads are free 2-way ds_read_b64. A from L2 (x-fragments, shared chip-wide).
__global__ __launch_bounds__(512, 2)
void hk2(const float* __restrict__ b1, uint8_t* __restrict__ ws)
{
  __shared__ uint8_t Wl[131072];
  __shared__ uint8_t xfer8[16384];
  const int blk = blockIdx.x;
  const int tt  = blk >> 5, cq = blk & 31;        // cols cq*64..+64 (chunks 2cq,2cq+1)
  const int tid = threadIdx.x, lane = tid & 63, wv = tid >> 6, l15 = lane & 15;
  const int s0  = wv*2;                           // this wave: strips s0, s0+1

  { // stage both W1 slices (byte-identical copy of proven layout)
    const uint64_t* src = (const uint64_t*)(ws + WS_W1F8 + (size_t)(cq*2)*65536);
    uint64_t* dst = (uint64_t*)Wl;
    #pragma unroll
    for (int k = 0; k < 32; ++k) dst[tid + k*512] = src[tid + k*512];
  }
  float b1v[4];
  #pragma unroll
  for (int f = 0; f < 4; ++f) b1v[f] = b1[cq*64 + f*16 + l15];
  __syncthreads();

  const uint8_t* xf = ws + WS_XF8 + lane*8;
  f32x4 acc[2][4] = {};
  for (int c0 = 0; c0 < 64; c0 += 8){
    const int j = c0 >> 3;
    const uint8_t* slot = xf + (size_t)(7 + tt - j)*XF8SLOT;
    uint64_t a0[8], a1[8];
    #pragma unroll
    for (int i = 0; i < 8; ++i){
      a0[i] = *(const uint64_t*)(slot + (size_t)( s0     *8 + i)*512);
      a1[i] = *(const uint64_t*)(slot + (size_t)((s0 + 1)*8 + i)*512);
    }
    #pragma unroll
    for (int i = 0; i < 8; ++i){
      const uint8_t* bp = Wl + (size_t)(c0 + i)*1024 + lane*8;
      #pragma unroll
      for (int f = 0; f < 4; ++f){
        long b = *(const long*)(bp + (f >> 1)*65536 + (f & 1)*512);
        acc[0][f] = mf(a0[i], b, acc[0][f]);
        acc[1][f] = mf(a1[i], b, acc[1][f]);
      }
    }
  }

  #pragma unroll
  for (int s = 0; s < 2; ++s)
    #pragma unroll
    for (int f = 0; f < 4; ++f)
      #pragma unroll
      for (int i = 0; i < 4; ++i){
        const int row = (s0 + s)*16 + ((lane >> 4) << 2) + i;
        float h = fmaxf(acc[s][f][i] + b1v[f], 0.f);
        int pk = __builtin_amdgcn_cvt_pk_fp8_f32(h, 0.f, 0, false);
        xfer8[row*64 + f*16 + l15] = (uint8_t)(pk & 0xFF);
      }
  __syncthreads();
  uint8_t* h8 = ws + WS_H8 + (size_t)tt*H8SLOT;
  #pragma unroll
  for (int r = 0; r < 4; ++r){        // 2048 u64 slots (16 strips x 2 chunks x 64)
    const int slot = tid + r*512;
    const int st = slot >> 7, cc = (slot >> 6) & 1, l = slot & 63;
    uint64_t v = *(const uint64_t*)
      &xfer8[(st*16 + (l & 15))*64 + cc*32 + ((l >> 4) << 3)];
    *(uint64_t*)(h8 + (size_t)(st*64 + cq*2 + cc)*512 + l*8) = v;
  }
}

// ============ corr2: corr(511-j)[c'] = (H(511-j) @ W2^T + b2)[c'] ============
// grid 576 = 288 (j,cb) units x 2 row-halves; 256 thr. W2 slice (64KB) in LDS.
__global__ __launch_bounds__(256, 2)
void corr2(const float* __restrict__ b2, uint8_t* __restrict__ ws)
{
  __shared__ uint8_t Wl[65536];
  const int blk = blockIdx.x;
  const int unit = blk >> 1, h = blk & 1;
  int j = 0, base = 0;
  while (unit - base >= 64 - 8*j){ base += 64 - 8*j; ++j; }
  const int cb = unit - base;
  const int colsj = 2048 - 256*j;
  const int tt = 7 - j;
  const int cum[8] = {0,2048,3840,5376,6656,7680,8448,8960};
  const int tid = threadIdx.x, lane = tid & 63, wv = tid >> 6, l15 = lane & 15;
  const int s0 = h*8 + wv*2;

  { // stage W2 slice cb
    const uint64_t* src = (const uint64_t*)(ws + WS_W2F8 + (size_t)cb*65536);
    uint64_t* dst = (uint64_t*)Wl;
    #pragma unroll
    for (int k = 0; k < 32; ++k) dst[tid + k*256] = src[tid + k*256];
  }
  const float b2v0 = b2[cb*32 + l15];
  const float b2v1 = b2[cb*32 + 16 + l15];
  __syncthreads();

  const uint8_t* h8 = ws + WS_H8 + (size_t)tt*H8SLOT + lane*8;
  const uint8_t* A0 = h8 + (size_t)( s0     *64)*512;
  const uint8_t* A1 = h8 + (size_t)((s0 + 1)*64)*512;

  f32x4 acc[2][2] = {{{0,0,0,0},{0,0,0,0}},{{0,0,0,0},{0,0,0,0}}};
  for (int c0 = 0; c0 < 64; c0 += 8){
    uint64_t a0[8], a1[8];
    #pragma unroll
    for (int i = 0; i < 8; ++i){
      a0[i] = *(const uint64_t*)(A0 + (size_t)(c0 + i)*512);
      a1[i] = *(const uint64_t*)(A1 + (size_t)(c0 + i)*512);
    }
    #pragma unroll
    for (int i = 0; i < 8; ++i){
      const uint8_t* bp = Wl + (size_t)(c0 + i)*1024 + lane*8;
      long b0 = *(const long*)bp, b1q = *(const long*)(bp + 512);
      acc[0][0] = mf(a0[i], b0,  acc[0][0]);
      acc[0][1] = mf(a0[i], b1q, acc[0][1]);
      acc[1][0] = mf(a1[i], b0,  acc[1][0]);
      acc[1][1] = mf(a1[i], b1q, acc[1][1]);
    }
  }

  __hip_bfloat16* cw = (__hip_bfloat16*)(ws + WS_CORR);
  const size_t slab = (size_t)cum[j]*256;
  #pragma unroll
  for (int s = 0; s < 2; ++s)
    #pragma unroll
    for (int f = 0; f < 2; ++f)
      #pragma unroll
      for (int i = 0; i < 4; ++i){
        const int row = (s0 + s)*16 + ((lane >> 4) << 2) + i;
        const int col = cb*32 + f*16 + l15;
        float v = acc[s][f][i] + (f ? b2v1 : b2v0);
        cw[slab + (size_t)row*colsj + col] = __float2bfloat16(v);
      }
}

// ============ asker: out[c] = sum_j LIN^j*UM*corr(511-j)[c-256j] + LIN^{J+1}*x ====
__global__ __launch_bounds__(256)
void asker(const float* __restrict__ x, float* __restrict__ out,
           const uint8_t* __restrict__ ws)
{
  const int r   = blockIdx.x;
  const int tid = threadIdx.x;
  const int cum[8] = {0,2048,3840,5376,6656,7680,8448,8960};
  const float UM = (float)(1.0 - 0.99999);
  const __hip_bfloat16* cw = (const __hip_bfloat16*)(ws + WS_CORR);

  for (int c = tid*8; c < tid*8 + 8; ++c){
    const int J = c >> 8;
    float acc = 0.f, lw = 1.f;
    for (int j = 0; j <= J; ++j){
      const int colsj = 2048 - 256*j;
      float cv = __bfloat162float(cw[(size_t)cum[j]*256 + (size_t)r*colsj + (c - 256*j)]);
      acc += lw * cv;
      lw  *= LINC;
    }
    const float xv = x[((size_t)(511 - J)*NB + r)*INW + (c & 255)];
    const float o  = UM*acc + lw*xv;
    if (c < STW) out[NB*INW + (size_t)r*STW + c] = o;   // states
    else         out[(size_t)r*INW + (c - STW)] = o;    // outputs
  }
}

extern "C" void kernel_launch(void* const* d_in, const int* in_sizes, int n_in,
                              void* d_out, int out_size, void* d_ws, size_t ws_size,
                              hipStream_t stream)
{
  const float* x   = (const float*)d_in[0];
  // d_in[1] (initial_state) provably does not reach the returned final carry
  const float* W1  = (const float*)d_in[2];
  const float* b1  = (const float*)d_in[3];
  const float* W2  = (const float*)d_in[4];
  const float* b2  = (const float*)d_in[5];
  float* out  = (float*)d_out;
  uint8_t* ws = (uint8_t*)d_ws;

  hipLaunchKernelGGL(prep,  dim3(316), dim3(256), 0, stream, x, W1, W2, ws);
  hipLaunchKernelGGL(hk2,   dim3(256), dim3(512), 0, stream, b1, ws);
  hipLaunchKernelGGL(corr2, dim3(576), dim3(256), 0, stream, b2, ws);
  hipLaunchKernelGGL(asker, dim3(256), dim3(256), 0, stream, x, out, ws);
}